// Round 5
// baseline (4016.806 us; speedup 1.0000x reference)
//
#include <hip/hip_runtime.h>

#define IMG_W 2048
#define NCH 3
#define BLK 4
#define NK 1024
#define DD 48              // BLK*BLK*NCH
#define WB 512             // blocks per image row
#define NL (WB * 512)      // 262144 blocks

// Kernel 0: cnorm[k] = sum_j cb[k][j]^2  (sequential fp32 FMA)
__global__ void vq_cnorm_kernel(const float* __restrict__ cb, float* __restrict__ cnorm) {
    int k = blockIdx.x * blockDim.x + threadIdx.x;
    if (k >= NK) return;
    const float* row = cb + k * DD;
    float s = 0.0f;
#pragma unroll
    for (int j = 0; j < DD; ++j) s = fmaf(row[j], row[j], s);
    cnorm[k] = s;
}

// Launder a zero through a VGPR so pointer arithmetic is formally divergent:
// forces the codebook stream onto the VECTOR memory path (global_load_dwordx4,
// vmcnt pipelining) instead of s_load/lgkmcnt serialization (R4's failure).
__device__ __forceinline__ int vzero() {
    int z;
    asm volatile("v_mov_b32 %0, 0" : "=v"(z));
    return z;
}

// 16 FMAs for float4 slice Q: 4 codes x this slice of x. Per-chain j order is
// ascending -> identical rounding to all passing rounds.
#define DOT4_Q(Q) do {                              \
        const float4 a = p0[Q];                     \
        const float4 b = p1[Q];                     \
        const float4 c = p2[Q];                     \
        const float4 d = p3[Q];                     \
        d0 = fmaf(x_##Q.x, a.x, d0);                \
        d0 = fmaf(x_##Q.y, a.y, d0);                \
        d0 = fmaf(x_##Q.z, a.z, d0);                \
        d0 = fmaf(x_##Q.w, a.w, d0);                \
        d1 = fmaf(x_##Q.x, b.x, d1);                \
        d1 = fmaf(x_##Q.y, b.y, d1);                \
        d1 = fmaf(x_##Q.z, b.z, d1);                \
        d1 = fmaf(x_##Q.w, b.w, d1);                \
        d2 = fmaf(x_##Q.x, c.x, d2);                \
        d2 = fmaf(x_##Q.y, c.y, d2);                \
        d2 = fmaf(x_##Q.z, c.z, d2);                \
        d2 = fmaf(x_##Q.w, c.w, d2);                \
        d3 = fmaf(x_##Q.x, d.x, d3);                \
        d3 = fmaf(x_##Q.y, d.y, d3);                \
        d3 = fmaf(x_##Q.z, d.z, d3);                \
        d3 = fmaf(x_##Q.w, d.w, d3);                \
    } while (0)

#define NORM_Q(Q) do {                              \
        nx = fmaf(x_##Q.x, x_##Q.x, nx);            \
        nx = fmaf(x_##Q.y, x_##Q.y, nx);            \
        nx = fmaf(x_##Q.z, x_##Q.z, nx);            \
        nx = fmaf(x_##Q.w, x_##Q.w, nx);            \
    } while (0)

__global__ __launch_bounds__(256, 4) void vq_main_kernel(const float* __restrict__ img,
                                                         const float* __restrict__ cb,
                                                         const float* __restrict__ cnorm,
                                                         float* __restrict__ out) {
    const int l  = blockIdx.x * blockDim.x + threadIdx.x;  // block id, < NL
    const int by = l >> 9;          // / WB
    const int bx = l & 511;         // % WB

    // ---- 4x4x3 image block into 12 NAMED float4 registers (48 VGPRs) ----
    const float* base = img + ((size_t)by * BLK * IMG_W + (size_t)bx * BLK) * NCH;
    const float* rp0 = base;
    const float* rp1 = base + (size_t)IMG_W * NCH;
    const float* rp2 = base + (size_t)2 * IMG_W * NCH;
    const float* rp3 = base + (size_t)3 * IMG_W * NCH;

    float4 x_0 = *(const float4*)(rp0 + 0), x_1  = *(const float4*)(rp0 + 4), x_2  = *(const float4*)(rp0 + 8);
    float4 x_3 = *(const float4*)(rp1 + 0), x_4  = *(const float4*)(rp1 + 4), x_5  = *(const float4*)(rp1 + 8);
    float4 x_6 = *(const float4*)(rp2 + 0), x_7  = *(const float4*)(rp2 + 4), x_8  = *(const float4*)(rp2 + 8);
    float4 x_9 = *(const float4*)(rp3 + 0), x_10 = *(const float4*)(rp3 + 4), x_11 = *(const float4*)(rp3 + 8);

    // ---- norm (sequential FMA, ascending j) ----
    float nx = 0.0f;
    NORM_Q(0); NORM_Q(1); NORM_Q(2); NORM_Q(3); NORM_Q(4); NORM_Q(5);
    NORM_Q(6); NORM_Q(7); NORM_Q(8); NORM_Q(9); NORM_Q(10); NORM_Q(11);

    // divergent-typed (laundered) bases -> vector memory path
    const int zoff = vzero();
    const float* cbv = cb + zoff;
    const float* cnv = cnorm + zoff;

    float best = __builtin_inff();
    int bestk = 0;

#pragma unroll 1
    for (int k = 0; k < NK; k += 4) {
        const float4* p0 = (const float4*)(cbv + (size_t)k * DD);  // code k
        const float4* p1 = p0 + 12;                                // k+1
        const float4* p2 = p0 + 24;                                // k+2
        const float4* p3 = p0 + 36;                                // k+3

        float d0 = 0.0f, d1 = 0.0f, d2 = 0.0f, d3 = 0.0f;
        DOT4_Q(0); DOT4_Q(1); DOT4_Q(2); DOT4_Q(3); DOT4_Q(4); DOT4_Q(5);
        DOT4_Q(6); DOT4_Q(7); DOT4_Q(8); DOT4_Q(9); DOT4_Q(10); DOT4_Q(11);

        const float cn0 = cnv[k], cn1 = cnv[k + 1], cn2 = cnv[k + 2], cn3 = cnv[k + 3];
        // fma(dot,-2,norm) == (norm - 2*dot) exactly (2*dot is exact)
        const float dA0 = fmaf(d0, -2.0f, nx) + cn0;
        const float dA1 = fmaf(d1, -2.0f, nx) + cn1;
        const float dA2 = fmaf(d2, -2.0f, nx) + cn2;
        const float dA3 = fmaf(d3, -2.0f, nx) + cn3;

        // strict-< tournament: first-occurrence argmin preserved
        const bool m1 = dA1 < dA0;
        const float w01 = m1 ? dA1 : dA0;
        const int  k01 = m1 ? k + 1 : k;
        const bool m3 = dA3 < dA2;
        const float w23 = m3 ? dA3 : dA2;
        const int  k23 = m3 ? k + 3 : k + 2;
        const bool mw = w23 < w01;
        const float w = mw ? w23 : w01;
        const int  wk = mw ? k23 : k01;
        if (w < best) { best = w; bestk = wk; }
    }

    // ---- gather chosen code, scatter back to image layout ----
    const float4* q = (const float4*)(cb + (size_t)bestk * DD);
    float* ob = out + ((size_t)by * BLK * IMG_W + (size_t)bx * BLK) * NCH;
#pragma unroll
    for (int r = 0; r < BLK; ++r) {
        float* rp = ob + (size_t)r * IMG_W * NCH;
        *(float4*)(rp + 0) = q[r * 3 + 0];
        *(float4*)(rp + 4) = q[r * 3 + 1];
        *(float4*)(rp + 8) = q[r * 3 + 2];
    }
}

extern "C" void kernel_launch(void* const* d_in, const int* in_sizes, int n_in,
                              void* d_out, int out_size, void* d_ws, size_t ws_size,
                              hipStream_t stream) {
    const float* img = (const float*)d_in[0];   // (2048, 2048, 3) fp32
    const float* cb  = (const float*)d_in[1];   // (1024, 16, 3) fp32
    float* out = (float*)d_out;                 // (2048, 2048, 3) fp32
    float* cnorm = (float*)d_ws;                // 1024 floats

    vq_cnorm_kernel<<<(NK + 255) / 256, 256, 0, stream>>>(cb, cnorm);
    vq_main_kernel<<<NL / 256, 256, 0, stream>>>(img, cb, cnorm, out);
}

// Round 6
// 333.478 us; speedup vs baseline: 12.0452x; 12.0452x over previous
//
#include <hip/hip_runtime.h>

#define IMG_W 2048
#define NCH 3
#define NK 1024
#define DD 48              // 4*4*3 floats per code / per block
#define NBX 512            // blocks per image row
#define NL (NBX * 512)     // 262144 blocks
#define NQUAD (NL / 4)     // 65536 quads (4 adjacent blocks per thread)
#define QPR (NBX / 4)      // 128 quads per row

// workspace layout (float offsets)
#define WS_CNORM 0
#define WS_B0 1024
#define WS_B1 (1024 + NL)
#define WS_K0 (1024 + 2 * NL)
#define WS_K1 (1024 + 3 * NL)
#define WS_FLOATS (1024 + 4 * NL)

// Kernel 0: cnorm[k] = sum_j cb[k][j]^2 (sequential fp32 FMA)
__global__ void vq_cnorm_kernel(const float* __restrict__ cb, float* __restrict__ cnorm) {
    int k = blockIdx.x * blockDim.x + threadIdx.x;
    if (k >= NK) return;
    const float* row = cb + k * DD;
    float s = 0.0f;
#pragma unroll
    for (int j = 0; j < DD; ++j) s = fmaf(row[j], row[j], s);
    cnorm[k] = s;
}

// norm accumulate over one float4 (ascending components)
#define NQ(N, V) do { N = fmaf(V.x, V.x, N); N = fmaf(V.y, V.y, N); \
                      N = fmaf(V.z, V.z, N); N = fmaf(V.w, V.w, N); } while (0)

// One float4 slice IDX of the two staged codes vs all 4 blocks' matching
// quads T0..T3: 32 FMAs, 8 independent chains, ascending-j per chain
// (identical rounding to every passing round).
#define STEP(IDX, T0, T1, T2, T3) do {                                  \
        const float4 a = c0p[IDX];                                      \
        const float4 b = c1p[IDX];                                      \
        d0_0 = fmaf(T0.x, a.x, d0_0); d0_0 = fmaf(T0.y, a.y, d0_0);     \
        d0_0 = fmaf(T0.z, a.z, d0_0); d0_0 = fmaf(T0.w, a.w, d0_0);     \
        d1_0 = fmaf(T0.x, b.x, d1_0); d1_0 = fmaf(T0.y, b.y, d1_0);     \
        d1_0 = fmaf(T0.z, b.z, d1_0); d1_0 = fmaf(T0.w, b.w, d1_0);     \
        d0_1 = fmaf(T1.x, a.x, d0_1); d0_1 = fmaf(T1.y, a.y, d0_1);     \
        d0_1 = fmaf(T1.z, a.z, d0_1); d0_1 = fmaf(T1.w, a.w, d0_1);     \
        d1_1 = fmaf(T1.x, b.x, d1_1); d1_1 = fmaf(T1.y, b.y, d1_1);     \
        d1_1 = fmaf(T1.z, b.z, d1_1); d1_1 = fmaf(T1.w, b.w, d1_1);     \
        d0_2 = fmaf(T2.x, a.x, d0_2); d0_2 = fmaf(T2.y, a.y, d0_2);     \
        d0_2 = fmaf(T2.z, a.z, d0_2); d0_2 = fmaf(T2.w, a.w, d0_2);     \
        d1_2 = fmaf(T2.x, b.x, d1_2); d1_2 = fmaf(T2.y, b.y, d1_2);     \
        d1_2 = fmaf(T2.z, b.z, d1_2); d1_2 = fmaf(T2.w, b.w, d1_2);     \
        d0_3 = fmaf(T3.x, a.x, d0_3); d0_3 = fmaf(T3.y, a.y, d0_3);     \
        d0_3 = fmaf(T3.z, a.z, d0_3); d0_3 = fmaf(T3.w, a.w, d0_3);     \
        d1_3 = fmaf(T3.x, b.x, d1_3); d1_3 = fmaf(T3.y, b.y, d1_3);     \
        d1_3 = fmaf(T3.z, b.z, d1_3); d1_3 = fmaf(T3.w, b.w, d1_3);     \
    } while (0)

#define MINUPD(M) do {                                                  \
        const float e0 = fmaf(d0_##M, -2.0f, n##M) + cn0;               \
        const float e1 = fmaf(d1_##M, -2.0f, n##M) + cn1;               \
        const bool s = e1 < e0;                                         \
        const float w = s ? e1 : e0;                                    \
        const int wk = s ? kg + 1 : kg;                                 \
        if (w < best##M) { best##M = w; bk##M = wk; }                   \
    } while (0)

// Partial kernel: thread = 4 adjacent blocks x HALF the codebook.
// Codebook half staged through LDS in two 256-code chunks (48 KB).
__global__ __launch_bounds__(256, 2) void vq_partial_kernel(const float* __restrict__ img,
                                                            const float* __restrict__ cb,
                                                            const float* __restrict__ cnorm,
                                                            float* __restrict__ b0out,
                                                            float* __restrict__ b1out,
                                                            int* __restrict__ k0out,
                                                            int* __restrict__ k1out) {
    __shared__ float4 lds[256 * 12];   // 48 KB: 256 codes x 12 quads

    const int tid   = threadIdx.x;
    const int W     = blockIdx.x;
    const int khalf = W & 1;
    const int q     = (W >> 1) * 256 + tid;   // quad id, < NQUAD
    const int by    = q >> 7;                  // quad row
    const int qcol  = q & 127;                 // quad col

    // ---- load 4 adjacent 4x4x3 blocks: 4 rows x 12 float4 (contiguous) ----
    const float4* img4 = (const float4*)img;
    const size_t rbase = (size_t)(by * 4) * 1536 + (size_t)qcol * 12;  // float4 idx
#define LOADROW(R) \
    const float4 t##R##_0  = img4[rbase + R * 1536 + 0];  \
    const float4 t##R##_1  = img4[rbase + R * 1536 + 1];  \
    const float4 t##R##_2  = img4[rbase + R * 1536 + 2];  \
    const float4 t##R##_3  = img4[rbase + R * 1536 + 3];  \
    const float4 t##R##_4  = img4[rbase + R * 1536 + 4];  \
    const float4 t##R##_5  = img4[rbase + R * 1536 + 5];  \
    const float4 t##R##_6  = img4[rbase + R * 1536 + 6];  \
    const float4 t##R##_7  = img4[rbase + R * 1536 + 7];  \
    const float4 t##R##_8  = img4[rbase + R * 1536 + 8];  \
    const float4 t##R##_9  = img4[rbase + R * 1536 + 9];  \
    const float4 t##R##_10 = img4[rbase + R * 1536 + 10]; \
    const float4 t##R##_11 = img4[rbase + R * 1536 + 11];
    LOADROW(0) LOADROW(1) LOADROW(2) LOADROW(3)
#undef LOADROW

    // ---- per-block norms (ascending j, same order as the dot chains) ----
    float n0 = 0.0f, n1 = 0.0f, n2 = 0.0f, n3 = 0.0f;
    NQ(n0, t0_0); NQ(n0, t0_1);  NQ(n0, t0_2);
    NQ(n0, t1_0); NQ(n0, t1_1);  NQ(n0, t1_2);
    NQ(n0, t2_0); NQ(n0, t2_1);  NQ(n0, t2_2);
    NQ(n0, t3_0); NQ(n0, t3_1);  NQ(n0, t3_2);
    NQ(n1, t0_3); NQ(n1, t0_4);  NQ(n1, t0_5);
    NQ(n1, t1_3); NQ(n1, t1_4);  NQ(n1, t1_5);
    NQ(n1, t2_3); NQ(n1, t2_4);  NQ(n1, t2_5);
    NQ(n1, t3_3); NQ(n1, t3_4);  NQ(n1, t3_5);
    NQ(n2, t0_6); NQ(n2, t0_7);  NQ(n2, t0_8);
    NQ(n2, t1_6); NQ(n2, t1_7);  NQ(n2, t1_8);
    NQ(n2, t2_6); NQ(n2, t2_7);  NQ(n2, t2_8);
    NQ(n2, t3_6); NQ(n2, t3_7);  NQ(n2, t3_8);
    NQ(n3, t0_9); NQ(n3, t0_10); NQ(n3, t0_11);
    NQ(n3, t1_9); NQ(n3, t1_10); NQ(n3, t1_11);
    NQ(n3, t2_9); NQ(n3, t2_10); NQ(n3, t2_11);
    NQ(n3, t3_9); NQ(n3, t3_10); NQ(n3, t3_11);

    float best0 = __builtin_inff(), best1 = __builtin_inff();
    float best2 = __builtin_inff(), best3 = __builtin_inff();
    int bk0 = 0, bk1 = 0, bk2 = 0, bk3 = 0;

    const float4* cb4 = (const float4*)cb;
    for (int c = 0; c < 2; ++c) {
        const int kbase = khalf * 512 + c * 256;
        __syncthreads();
        const float4* src = cb4 + (size_t)kbase * 12;
#pragma unroll
        for (int p = 0; p < 12; ++p) lds[p * 256 + tid] = src[p * 256 + tid];
        __syncthreads();

#pragma unroll 1
        for (int kk = 0; kk < 256; kk += 2) {
            const float4* c0p = &lds[kk * 12];   // wave-uniform -> broadcast
            const float4* c1p = c0p + 12;
            const int kg = kbase + kk;

            float d0_0 = 0.0f, d0_1 = 0.0f, d0_2 = 0.0f, d0_3 = 0.0f;
            float d1_0 = 0.0f, d1_1 = 0.0f, d1_2 = 0.0f, d1_3 = 0.0f;

            STEP(0,  t0_0, t0_3, t0_6, t0_9);
            STEP(1,  t0_1, t0_4, t0_7, t0_10);
            STEP(2,  t0_2, t0_5, t0_8, t0_11);
            STEP(3,  t1_0, t1_3, t1_6, t1_9);
            STEP(4,  t1_1, t1_4, t1_7, t1_10);
            STEP(5,  t1_2, t1_5, t1_8, t1_11);
            STEP(6,  t2_0, t2_3, t2_6, t2_9);
            STEP(7,  t2_1, t2_4, t2_7, t2_10);
            STEP(8,  t2_2, t2_5, t2_8, t2_11);
            STEP(9,  t3_0, t3_3, t3_6, t3_9);
            STEP(10, t3_1, t3_4, t3_7, t3_10);
            STEP(11, t3_2, t3_5, t3_8, t3_11);

            const float cn0 = cnorm[kg], cn1 = cnorm[kg + 1];
            MINUPD(0); MINUPD(1); MINUPD(2); MINUPD(3);
        }
    }

    // one float4 + one int4 per thread: blocks 4q..4q+3
    ((float4*)(khalf ? b1out : b0out))[q] = make_float4(best0, best1, best2, best3);
    ((int4*)(khalf ? k1out : k0out))[q]   = make_int4(bk0, bk1, bk2, bk3);
}

// Combine halves (lower-k wins ties: strict <), gather code, scatter to image.
__global__ __launch_bounds__(256) void vq_combine_kernel(const float* __restrict__ cb,
                                                         const float* __restrict__ b0,
                                                         const float* __restrict__ b1,
                                                         const int* __restrict__ k0,
                                                         const int* __restrict__ k1,
                                                         float* __restrict__ out) {
    const int l = blockIdx.x * blockDim.x + threadIdx.x;   // block id
    const float e0 = b0[l], e1 = b1[l];
    const int k = (e1 < e0) ? k1[l] : k0[l];

    const int by = l >> 9;
    const int bx = l & 511;
    const float4* qp = (const float4*)(cb) + (size_t)k * 12;
    float4* out4 = (float4*)out;
    const size_t obase = (size_t)(by * 4) * 1536 + (size_t)bx * 3;
#pragma unroll
    for (int r = 0; r < 4; ++r) {
        out4[obase + r * 1536 + 0] = qp[r * 3 + 0];
        out4[obase + r * 1536 + 1] = qp[r * 3 + 1];
        out4[obase + r * 1536 + 2] = qp[r * 3 + 2];
    }
}

// ---------------- fallback (proven R3 kernel, M=2 full-K) ----------------
#define DOT_Q(Q) do {                                   \
        const float4 a = c0p[Q];                        \
        const float4 b = c1p[Q];                        \
        d00 = fmaf(xa_##Q.x, a.x, d00); d00 = fmaf(xa_##Q.y, a.y, d00); \
        d00 = fmaf(xa_##Q.z, a.z, d00); d00 = fmaf(xa_##Q.w, a.w, d00); \
        d01 = fmaf(xa_##Q.x, b.x, d01); d01 = fmaf(xa_##Q.y, b.y, d01); \
        d01 = fmaf(xa_##Q.z, b.z, d01); d01 = fmaf(xa_##Q.w, b.w, d01); \
        d10 = fmaf(xb_##Q.x, a.x, d10); d10 = fmaf(xb_##Q.y, a.y, d10); \
        d10 = fmaf(xb_##Q.z, a.z, d10); d10 = fmaf(xb_##Q.w, a.w, d10); \
        d11 = fmaf(xb_##Q.x, b.x, d11); d11 = fmaf(xb_##Q.y, b.y, d11); \
        d11 = fmaf(xb_##Q.z, b.z, d11); d11 = fmaf(xb_##Q.w, b.w, d11); \
    } while (0)

__global__ __launch_bounds__(256, 2) void vq_main_m2(const float* __restrict__ img,
                                                     const float* __restrict__ cb,
                                                     const float* __restrict__ cnorm,
                                                     float* __restrict__ out) {
    __shared__ float4 lds[256 * 12];
    const int tid = threadIdx.x;
    const int t   = blockIdx.x * blockDim.x + tid;
    const int by  = t >> 8;
    const int bx0 = (t & 255) * 2;

    const float* base = img + ((size_t)by * 4 * IMG_W + (size_t)bx0 * 4) * NCH;
    const float* rp0 = base;
    const float* rp1 = base + (size_t)IMG_W * NCH;
    const float* rp2 = base + (size_t)2 * IMG_W * NCH;
    const float* rp3 = base + (size_t)3 * IMG_W * NCH;

    float4 xa_0 = *(const float4*)(rp0 + 0), xa_1  = *(const float4*)(rp0 + 4), xa_2  = *(const float4*)(rp0 + 8);
    float4 xb_0 = *(const float4*)(rp0 + 12), xb_1 = *(const float4*)(rp0 + 16), xb_2 = *(const float4*)(rp0 + 20);
    float4 xa_3 = *(const float4*)(rp1 + 0), xa_4  = *(const float4*)(rp1 + 4), xa_5  = *(const float4*)(rp1 + 8);
    float4 xb_3 = *(const float4*)(rp1 + 12), xb_4 = *(const float4*)(rp1 + 16), xb_5 = *(const float4*)(rp1 + 20);
    float4 xa_6 = *(const float4*)(rp2 + 0), xa_7  = *(const float4*)(rp2 + 4), xa_8  = *(const float4*)(rp2 + 8);
    float4 xb_6 = *(const float4*)(rp2 + 12), xb_7 = *(const float4*)(rp2 + 16), xb_8 = *(const float4*)(rp2 + 20);
    float4 xa_9 = *(const float4*)(rp3 + 0), xa_10 = *(const float4*)(rp3 + 4), xa_11 = *(const float4*)(rp3 + 8);
    float4 xb_9 = *(const float4*)(rp3 + 12), xb_10 = *(const float4*)(rp3 + 16), xb_11 = *(const float4*)(rp3 + 20);

    float na = 0.0f, nb = 0.0f;
    NQ(na, xa_0); NQ(na, xa_1); NQ(na, xa_2); NQ(na, xa_3); NQ(na, xa_4); NQ(na, xa_5);
    NQ(na, xa_6); NQ(na, xa_7); NQ(na, xa_8); NQ(na, xa_9); NQ(na, xa_10); NQ(na, xa_11);
    NQ(nb, xb_0); NQ(nb, xb_1); NQ(nb, xb_2); NQ(nb, xb_3); NQ(nb, xb_4); NQ(nb, xb_5);
    NQ(nb, xb_6); NQ(nb, xb_7); NQ(nb, xb_8); NQ(nb, xb_9); NQ(nb, xb_10); NQ(nb, xb_11);

    float bestA = __builtin_inff(), bestB = __builtin_inff();
    int ka = 0, kb = 0;

    for (int c = 0; c < 4; ++c) {
        __syncthreads();
        const float4* src = (const float4*)(cb + (size_t)c * 256 * DD);
#pragma unroll
        for (int p = 0; p < 12; ++p) lds[p * 256 + tid] = src[p * 256 + tid];
        __syncthreads();
#pragma unroll 1
        for (int kk = 0; kk < 256; kk += 2) {
            const float4* c0p = &lds[kk * 12];
            const float4* c1p = c0p + 12;
            const int k = c * 256 + kk;
            float d00 = 0.0f, d01 = 0.0f, d10 = 0.0f, d11 = 0.0f;
            DOT_Q(0); DOT_Q(1); DOT_Q(2); DOT_Q(3); DOT_Q(4); DOT_Q(5);
            DOT_Q(6); DOT_Q(7); DOT_Q(8); DOT_Q(9); DOT_Q(10); DOT_Q(11);
            const float cn0 = cnorm[k], cn1 = cnorm[k + 1];
            const float dA0 = fmaf(d00, -2.0f, na) + cn0;
            const float dA1 = fmaf(d01, -2.0f, na) + cn1;
            const float dB0 = fmaf(d10, -2.0f, nb) + cn0;
            const float dB1 = fmaf(d11, -2.0f, nb) + cn1;
            const bool a1 = dA1 < dA0;
            const float wA = a1 ? dA1 : dA0;
            const int  wAk = a1 ? k + 1 : k;
            if (wA < bestA) { bestA = wA; ka = wAk; }
            const bool b1 = dB1 < dB0;
            const float wB = b1 ? dB1 : dB0;
            const int  wBk = b1 ? k + 1 : k;
            if (wB < bestB) { bestB = wB; kb = wBk; }
        }
    }

    const float4* qa = (const float4*)(cb + (size_t)ka * DD);
    const float4* qb = (const float4*)(cb + (size_t)kb * DD);
    float* ob = out + ((size_t)by * 4 * IMG_W + (size_t)bx0 * 4) * NCH;
#pragma unroll
    for (int r = 0; r < 4; ++r) {
        float* rp = ob + (size_t)r * IMG_W * NCH;
        *(float4*)(rp + 0)  = qa[r * 3 + 0];
        *(float4*)(rp + 4)  = qa[r * 3 + 1];
        *(float4*)(rp + 8)  = qa[r * 3 + 2];
        *(float4*)(rp + 12) = qb[r * 3 + 0];
        *(float4*)(rp + 16) = qb[r * 3 + 1];
        *(float4*)(rp + 20) = qb[r * 3 + 2];
    }
}

extern "C" void kernel_launch(void* const* d_in, const int* in_sizes, int n_in,
                              void* d_out, int out_size, void* d_ws, size_t ws_size,
                              hipStream_t stream) {
    const float* img = (const float*)d_in[0];   // (2048, 2048, 3) fp32
    const float* cb  = (const float*)d_in[1];   // (1024, 16, 3) fp32
    float* out = (float*)d_out;                 // (2048, 2048, 3) fp32
    float* ws  = (float*)d_ws;
    float* cnorm = ws + WS_CNORM;

    vq_cnorm_kernel<<<(NK + 255) / 256, 256, 0, stream>>>(cb, cnorm);

    if (ws_size >= (size_t)WS_FLOATS * sizeof(float)) {
        vq_partial_kernel<<<NQUAD / 256 * 2, 256, 0, stream>>>(
            img, cb, cnorm, ws + WS_B0, ws + WS_B1, (int*)(ws + WS_K0), (int*)(ws + WS_K1));
        vq_combine_kernel<<<NL / 256, 256, 0, stream>>>(
            cb, ws + WS_B0, ws + WS_B1, (const int*)(ws + WS_K0), (const int*)(ws + WS_K1), out);
    } else {
        vq_main_m2<<<(NL / 2) / 256, 256, 0, stream>>>(img, cb, cnorm, out);
    }
}

// Round 7
// 178.048 us; speedup vs baseline: 22.5603x; 1.8730x over previous
//
#include <hip/hip_runtime.h>

#define NK 1024
#define DD 48              // 4*4*3 floats per code / per block
#define NBX 512            // blocks per image row
#define NL (NBX * 512)     // 262144 blocks
#define NTILE 32           // 32 code-tiles of 32 codes

// workspace layout (float offsets). Needs ~300KB; R6 proved ws >= 4.2MB.
#define WS_CNORM 0
#define WS_BFRAG 1024
#define FRAGS_PER_LEVEL (32 * 3 * 64)     // tiles * ksteps * lanes = 6144 frags
#define WS_FLOATS (1024 + 3 * FRAGS_PER_LEVEL * 4)

typedef __attribute__((ext_vector_type(8)))  short bf16x8;
typedef __attribute__((ext_vector_type(16))) float f32x16;

// fp32 -> bf16 bits, round-to-nearest-even (finite inputs)
__device__ __forceinline__ unsigned int rneb(float x) {
    unsigned int u = __float_as_uint(x);
    return (u + 0x7FFFu + ((u >> 16) & 1u)) >> 16;
}
__device__ __forceinline__ float bftof(unsigned int b) {
    return __uint_as_float(b << 16);
}
// 3-term bf16 split: x = h + m + l (h,m residual splits are exact; l ~2^-24 rel)
__device__ __forceinline__ void split3(float x, unsigned int& hb, unsigned int& mb, unsigned int& lb) {
    hb = rneb(x);
    float r1 = x - bftof(hb);
    mb = rneb(r1);
    float r2 = r1 - bftof(mb);
    lb = rneb(r2);
}

// cnorm[k] = sum_j cb[k][j]^2 (fp32 sequential FMA, as all passing rounds)
__global__ void vq_cnorm_kernel(const float* __restrict__ cb, float* __restrict__ cnorm) {
    int k = blockIdx.x * blockDim.x + threadIdx.x;
    if (k >= NK) return;
    const float* row = cb + k * DD;
    float s = 0.0f;
#pragma unroll
    for (int j = 0; j < DD; ++j) s = fmaf(row[j], row[j], s);
    cnorm[k] = s;
}

// B prep: pack codebook into MFMA B-fragments for levels h/m/l.
// Frag (t, s, lane): code = t*32 + (lane&31), j = s*16 + (lane>>5)*8 + e.
__global__ void vq_bprep_kernel(const float* __restrict__ cb, float* __restrict__ ws) {
    int tid = blockIdx.x * blockDim.x + threadIdx.x;
    if (tid >= FRAGS_PER_LEVEL) return;
    int lane = tid & 63;
    int s    = (tid >> 6) % 3;
    int t    = tid / (3 * 64);
    int col = lane & 31, lh = lane >> 5;
    int code = t * 32 + col;
    int j0 = s * 16 + lh * 8;
    const float* src = cb + code * DD + j0;
    bf16x8 vh, vm, vl;
#pragma unroll
    for (int e = 0; e < 8; ++e) {
        unsigned int hb, mb, lb;
        split3(src[e], hb, mb, lb);
        vh[e] = (short)hb; vm[e] = (short)mb; vl[e] = (short)lb;
    }
    bf16x8* base = (bf16x8*)(ws + WS_BFRAG);
    int fi = (t * 3 + s) * 64 + lane;
    base[0 * FRAGS_PER_LEVEL + fi] = vh;
    base[1 * FRAGS_PER_LEVEL + fi] = vm;
    base[2 * FRAGS_PER_LEVEL + fi] = vl;
}

#define MFMA __builtin_amdgcn_mfma_f32_32x32x16_bf16

// Main: wave = 64 blocks (two 32x32 row-tiles) x all 1024 codes.
// fp32 GEMM emulated by 6 bf16 products (hh,hm,mh,hl,lh,mm) -> ~2^-24 accuracy.
__global__ __launch_bounds__(256, 2) void vq_mfma_kernel(const float* __restrict__ img,
                                                         const float* __restrict__ cb,
                                                         const float* __restrict__ ws,
                                                         float* __restrict__ out) {
    __shared__ int lds_bk[4 * 64];
    const int lane  = threadIdx.x & 63;
    const int wid   = threadIdx.x >> 6;
    const int wave  = blockIdx.x * 4 + wid;
    const int wbase = wave * 64;
    const int col = lane & 31, lh = lane >> 5;
    const float* cnorm = ws + WS_CNORM;
    const bf16x8* bfrag = (const bf16x8*)(ws + WS_BFRAG);

    // ---- load + split image A-fragments (stay in VGPRs for whole K loop) ----
    bf16x8 Ah[2][3], Am[2][3], Al[2][3];
#pragma unroll
    for (int T = 0; T < 2; ++T) {
        const int b = wbase + T * 32 + col;
        const int by4 = (b >> 9) * 4, bx = b & 511;
#pragma unroll
        for (int s = 0; s < 3; ++s) {
            const int j0 = s * 16 + lh * 8;
            const int ja = j0, jb = j0 + 4;
            const int ra = (ja * 683) >> 13, ca = ja - 12 * ra;   // j/12, j%12
            const int rb = (jb * 683) >> 13, cb2 = jb - 12 * rb;
            const float4 fa = *(const float4*)(img + ((size_t)(by4 + ra) * 2048 + bx * 4) * 3 + ca);
            const float4 fb = *(const float4*)(img + ((size_t)(by4 + rb) * 2048 + bx * 4) * 3 + cb2);
            const float f[8] = {fa.x, fa.y, fa.z, fa.w, fb.x, fb.y, fb.z, fb.w};
#pragma unroll
            for (int e = 0; e < 8; ++e) {
                unsigned int hb, mb, lb;
                split3(f[e], hb, mb, lb);
                Ah[T][s][e] = (short)hb; Am[T][s][e] = (short)mb; Al[T][s][e] = (short)lb;
            }
        }
    }

    float best0[16], best1[16];
    int bk0[16], bk1[16];
#pragma unroll
    for (int q = 0; q < 16; ++q) { best0[q] = best1[q] = __builtin_inff(); bk0[q] = bk1[q] = 0; }

#pragma unroll 1
    for (int t = 0; t < NTILE; ++t) {
        bf16x8 Bh[3], Bm[3], Bl[3];
#pragma unroll
        for (int s = 0; s < 3; ++s) {
            const int fi = (t * 3 + s) * 64 + lane;
            Bh[s] = bfrag[fi];
            Bm[s] = bfrag[FRAGS_PER_LEVEL + fi];
            Bl[s] = bfrag[2 * FRAGS_PER_LEVEL + fi];
        }
        const float cn = cnorm[t * 32 + col];
        const int   kl = t * 32 + col;

        f32x16 a0, a1;
#pragma unroll
        for (int q = 0; q < 16; ++q) { a0[q] = 0.0f; a1[q] = 0.0f; }

        // 6 products x 3 ksteps, small->large, T-interleaved (2 indep chains)
#pragma unroll
        for (int s = 0; s < 3; ++s) {
            a0 = MFMA(Am[0][s], Bm[s], a0, 0, 0, 0);
            a1 = MFMA(Am[1][s], Bm[s], a1, 0, 0, 0);
            a0 = MFMA(Ah[0][s], Bl[s], a0, 0, 0, 0);
            a1 = MFMA(Ah[1][s], Bl[s], a1, 0, 0, 0);
            a0 = MFMA(Al[0][s], Bh[s], a0, 0, 0, 0);
            a1 = MFMA(Al[1][s], Bh[s], a1, 0, 0, 0);
            a0 = MFMA(Am[0][s], Bh[s], a0, 0, 0, 0);
            a1 = MFMA(Am[1][s], Bh[s], a1, 0, 0, 0);
            a0 = MFMA(Ah[0][s], Bm[s], a0, 0, 0, 0);
            a1 = MFMA(Ah[1][s], Bm[s], a1, 0, 0, 0);
            a0 = MFMA(Ah[0][s], Bh[s], a0, 0, 0, 0);
            a1 = MFMA(Ah[1][s], Bh[s], a1, 0, 0, 0);
        }

        // e = -2*dot + cn  (xnorm dropped: argmin-invariant constant per row)
#pragma unroll
        for (int q = 0; q < 16; ++q) {
            const float e0 = fmaf(a0[q], -2.0f, cn);
            if (e0 < best0[q]) { best0[q] = e0; bk0[q] = kl; }
            const float e1 = fmaf(a1[q], -2.0f, cn);
            if (e1 < best1[q]) { best1[q] = e1; bk1[q] = kl; }
        }
    }

    // ---- cross-lane lexicographic (d,k) reduce within each 32-lane half ----
#pragma unroll
    for (int q = 0; q < 16; ++q) {
        float d0 = best0[q]; int K0 = bk0[q];
        float d1 = best1[q]; int K1 = bk1[q];
#pragma unroll
        for (int m = 1; m < 32; m <<= 1) {
            float od = __shfl_xor(d0, m, 64); int ok = __shfl_xor(K0, m, 64);
            bool tk = (od < d0) || (od == d0 && ok < K0);
            d0 = tk ? od : d0; K0 = tk ? ok : K0;
            od = __shfl_xor(d1, m, 64); ok = __shfl_xor(K1, m, 64);
            tk = (od < d1) || (od == d1 && ok < K1);
            d1 = tk ? od : d1; K1 = tk ? ok : K1;
        }
        const int row32 = (q & 3) + 8 * (q >> 2) + 4 * lh;   // verified C-row map
        if ((lane & 31) == q) {
            lds_bk[wid * 64 + row32]      = K0;   // T=0 blocks
            lds_bk[wid * 64 + 32 + row32] = K1;   // T=1 blocks
        }
    }

    // ---- gather chosen code (fp32 original), scatter to image layout ----
    const int myk = lds_bk[wid * 64 + lane];     // block wbase+lane
    const int b = wbase + lane;
    const int by4 = (b >> 9) * 4, bx = b & 511;
    const float4* qp = (const float4*)(cb + (size_t)myk * DD);
#pragma unroll
    for (int r = 0; r < 4; ++r) {
        float4* op = (float4*)(out + ((size_t)(by4 + r) * 2048 + bx * 4) * 3);
        op[0] = qp[r * 3 + 0];
        op[1] = qp[r * 3 + 1];
        op[2] = qp[r * 3 + 2];
    }
}

extern "C" void kernel_launch(void* const* d_in, const int* in_sizes, int n_in,
                              void* d_out, int out_size, void* d_ws, size_t ws_size,
                              hipStream_t stream) {
    const float* img = (const float*)d_in[0];   // (2048, 2048, 3) fp32
    const float* cb  = (const float*)d_in[1];   // (1024, 16, 3) fp32
    float* out = (float*)d_out;                 // (2048, 2048, 3) fp32
    float* ws  = (float*)d_ws;

    vq_cnorm_kernel<<<(NK + 255) / 256, 256, 0, stream>>>(cb, ws + WS_CNORM);
    vq_bprep_kernel<<<(FRAGS_PER_LEVEL + 255) / 256, 256, 0, stream>>>(cb, ws);
    vq_mfma_kernel<<<NL / 64 / 4, 256, 0, stream>>>(img, cb, ws, out);
}